// Round 2
// baseline (1268.900 us; speedup 1.0000x reference)
//
#include <hip/hip_runtime.h>
#include <hip/hip_bf16.h>

// Flash attention fwd, B=4 H=16 S=2048 D=128. fp32 in/out.
// QK^T in split-bf16 (qh*kh + qh*kl + ql*kh) for fp32-grade logits; PV in bf16.
// Block = 64 Q-rows of one head; 4 waves, wave owns 16 rows.
// Online softmax in exp2 domain; P via wave-private LDS round-trip (C->A layout).

typedef __bf16 bf16;
typedef __attribute__((ext_vector_type(4))) __bf16 bf16x4;
typedef __attribute__((ext_vector_type(8))) __bf16 bf16x8;
typedef __attribute__((ext_vector_type(4))) float f32x4;

constexpr int S_ = 2048;
constexpr int D_ = 128;
constexpr int BM = 64;      // Q rows per block
constexpr int BN = 64;      // K rows per tile
constexpr int PK = D_ + 8;  // 136 bf16 pitch (+16B pad)
constexpr int PVT = BN + 8; // 72 bf16 pitch for V^T
constexpr int PP = BN + 8;  // 72 bf16 pitch for P

__global__ __launch_bounds__(256) void attn_fwd(
    const float* __restrict__ q, const float* __restrict__ kg,
    const float* __restrict__ vg, const float* __restrict__ sc,
    float* __restrict__ out)
{
    __shared__ __align__(16) bf16 Kh[BN * PK];      // 17408 B  K hi
    __shared__ __align__(16) bf16 Kl[BN * PK];      // 17408 B  K lo (residual)
    __shared__ __align__(16) bf16 Vs[D_ * PVT];     // 18432 B  Vs[d][t] = V[t][d]
    __shared__ __align__(16) bf16 Ps[4 * 16 * PP];  //  9216 B  wave-private 16x64 P

    const int tid  = threadIdx.x;
    const int wave = tid >> 6;
    const int lane = tid & 63;
    const int l16  = lane & 15;
    const int quad = lane >> 4;

    const int qt = blockIdx.x;   // Q-tile 0..31
    const int bh = blockIdx.y;   // head 0..63

    // fold log2(e): softmax_e(s*qk) == softmax_2(s*log2e*qk). scale may be <0.
    const float scale = sc[bh] * 1.44269504088896f;

    const float* qbase = q  + ((size_t)bh * S_ + (size_t)qt * BM) * D_;
    const float* kbase = kg + (size_t)bh * S_ * D_;
    const float* vbase = vg + (size_t)bh * S_ * D_;

    // Q fragments in registers (A-layout: m=l16 within wave's 16 rows, k=quad*8+j +32*ks)
    bf16x8 qh[4], ql[4];
    {
        const float* qrow = qbase + (size_t)(wave * 16 + l16) * D_ + quad * 8;
#pragma unroll
        for (int ks = 0; ks < 4; ++ks) {
            float x[8];
            *(float4*)&x[0] = *(const float4*)(qrow + ks * 32);
            *(float4*)&x[4] = *(const float4*)(qrow + ks * 32 + 4);
#pragma unroll
            for (int j = 0; j < 8; ++j) {
                bf16 h = (bf16)x[j];
                qh[ks][j] = h;
                ql[ks][j] = (bf16)(x[j] - (float)h);
            }
        }
    }

    f32x4 O[8];                       // O[dblk][reg]: row=quad*4+reg, col=l16+16*dblk
#pragma unroll
    for (int i = 0; i < 8; ++i) O[i] = (f32x4){0.f, 0.f, 0.f, 0.f};
    float mrow[4] = {-1e30f, -1e30f, -1e30f, -1e30f};
    float lrow[4] = {0.f, 0.f, 0.f, 0.f};

    for (int it = 0; it < S_ / BN; ++it) {
        __syncthreads();  // protect Kh/Kl/Vs from previous iteration's readers

        // ---- stage K tile: 64x128 fp32 -> bf16 hi/lo in LDS ----
        {
            const float* kt = kbase + (size_t)it * BN * D_;
#pragma unroll
            for (int r = 0; r < 8; ++r) {
                int i = tid + r * 256;          // 2048 chunks of 4 floats
                int row = i >> 5, c = i & 31;   // 32 chunks per 128-col row
                float4 v = *(const float4*)(kt + row * D_ + c * 4);
                const float* x = (const float*)&v;
                bf16x4 h4, l4;
#pragma unroll
                for (int j = 0; j < 4; ++j) {
                    bf16 h = (bf16)x[j];
                    h4[j] = h;
                    l4[j] = (bf16)(x[j] - (float)h);
                }
                *(bf16x4*)&Kh[row * PK + c * 4] = h4;
                *(bf16x4*)&Kl[row * PK + c * 4] = l4;
            }
            // ---- stage V transposed: Vs[d][t], bf16 ----
            const float* vt = vbase + (size_t)it * BN * D_;
#pragma unroll
            for (int r = 0; r < 4; ++r) {
                int i = tid + r * 256;          // 1024 tasks: 32 t-pairs x 32 d-chunks
                int p = i & 31;                 // t-pair (rows 2p, 2p+1)
                int c = i >> 5;                 // d-chunk (cols 4c..4c+3)
                const float* v0 = vt + (2 * p) * D_ + c * 4;
                float4 a0 = *(const float4*)v0;
                float4 a1 = *(const float4*)(v0 + D_);
                const float* x0 = (const float*)&a0;
                const float* x1 = (const float*)&a1;
#pragma unroll
                for (int j = 0; j < 4; ++j) {
                    union { ushort2 u; bf16 b[2]; } pr;
                    pr.b[0] = (bf16)x0[j];
                    pr.b[1] = (bf16)x1[j];
                    *(ushort2*)&Vs[(c * 4 + j) * PVT + 2 * p] = pr.u;
                }
            }
        }
        __syncthreads();

        // ---- QK^T: wave computes S[16 x 64], split-bf16 (3 MFMAs per k-step) ----
        f32x4 sacc[4];
#pragma unroll
        for (int nb = 0; nb < 4; ++nb) {
            f32x4 acc = (f32x4){0.f, 0.f, 0.f, 0.f};
#pragma unroll
            for (int ks = 0; ks < 4; ++ks) {
                int off = (nb * 16 + l16) * PK + ks * 32 + quad * 8;
                bf16x8 kh = *(const bf16x8*)&Kh[off];
                bf16x8 kl = *(const bf16x8*)&Kl[off];
                acc = __builtin_amdgcn_mfma_f32_16x16x32_bf16(qh[ks], kh, acc, 0, 0, 0);
                acc = __builtin_amdgcn_mfma_f32_16x16x32_bf16(qh[ks], kl, acc, 0, 0, 0);
                acc = __builtin_amdgcn_mfma_f32_16x16x32_bf16(ql[ks], kh, acc, 0, 0, 0);
            }
            sacc[nb] = acc;
        }

        // ---- online softmax (exp2 domain); scale BEFORE max (scale may be <0) ----
        float sv[4][4];
#pragma unroll
        for (int nb = 0; nb < 4; ++nb)
#pragma unroll
            for (int r = 0; r < 4; ++r)
                sv[nb][r] = sacc[nb][r] * scale;

#pragma unroll
        for (int r = 0; r < 4; ++r) {
            float m0 = fmaxf(fmaxf(sv[0][r], sv[1][r]), fmaxf(sv[2][r], sv[3][r]));
#pragma unroll
            for (int off = 8; off >= 1; off >>= 1)
                m0 = fmaxf(m0, __shfl_xor(m0, off, 64));
            float mnew  = fmaxf(mrow[r], m0);
            float alpha = exp2f(mrow[r] - mnew);
            mrow[r] = mnew;
            float psum = 0.f;
#pragma unroll
            for (int nb = 0; nb < 4; ++nb) {
                float pe = exp2f(sv[nb][r] - mnew);
                sv[nb][r] = pe;
                psum += pe;
            }
#pragma unroll
            for (int off = 8; off >= 1; off >>= 1)
                psum += __shfl_xor(psum, off, 64);
            lrow[r] = lrow[r] * alpha + psum;
#pragma unroll
            for (int d = 0; d < 8; ++d) O[d][r] *= alpha;
        }

        // ---- P: C-layout regs -> wave-private LDS (read back in A-layout) ----
        bf16* pw = &Ps[wave * 16 * PP];
#pragma unroll
        for (int nb = 0; nb < 4; ++nb)
#pragma unroll
            for (int r = 0; r < 4; ++r)
                pw[(quad * 4 + r) * PP + nb * 16 + l16] = (bf16)sv[nb][r];
        // same-wave DS ops execute in order; compiler inserts lgkmcnt waits.

        // ---- PV: O[16 x 128] += P[16 x 64] * V[64 x 128] ----
#pragma unroll
        for (int ts = 0; ts < 2; ++ts) {
            bf16x8 pa = *(const bf16x8*)&pw[l16 * PP + ts * 32 + quad * 8];
#pragma unroll
            for (int d = 0; d < 8; ++d) {
                bf16x8 vb = *(const bf16x8*)&Vs[(d * 16 + l16) * PVT + ts * 32 + quad * 8];
                O[d] = __builtin_amdgcn_mfma_f32_16x16x32_bf16(pa, vb, O[d], 0, 0, 0);
            }
        }
    }

    // ---- epilogue: O /= l, fp32 store ----
    float rl[4];
#pragma unroll
    for (int r = 0; r < 4; ++r) rl[r] = 1.0f / lrow[r];
    float* og = out + ((size_t)bh * S_ + (size_t)qt * BM + wave * 16) * D_;
#pragma unroll
    for (int d = 0; d < 8; ++d)
#pragma unroll
        for (int r = 0; r < 4; ++r)
            og[(quad * 4 + r) * D_ + d * 16 + l16] = O[d][r] * rl[r];
}

extern "C" void kernel_launch(void* const* d_in, const int* in_sizes, int n_in,
                              void* d_out, int out_size, void* d_ws, size_t ws_size,
                              hipStream_t stream) {
    const float* q  = (const float*)d_in[0];
    const float* k  = (const float*)d_in[1];
    const float* v  = (const float*)d_in[2];
    const float* sc = (const float*)d_in[3];
    float* o = (float*)d_out;
    dim3 grid(S_ / BM, 4 * 16);   // 32 Q-tiles x 64 heads
    attn_fwd<<<grid, 256, 0, stream>>>(q, k, v, sc, o);
}

// Round 3
// 789.015 us; speedup vs baseline: 1.6082x; 1.6082x over previous
//
#include <hip/hip_runtime.h>
#include <hip/hip_bf16.h>

// Flash attention fwd, B=4 H=16 S=2048 D=128. fp32 in/out.
// QK^T split-bf16 (qh*kh + qh*kl + ql*kh), scale*log2(e) pre-folded into Q.
// PV in bf16. Block = 64 Q-rows, 4 waves x 16 rows. BN=32 key tile -> LDS = 32 KB
// exactly -> 4 blocks/CU (16 waves, 4/SIMD) vs round-2's 2 blocks (latency-bound).
// Online softmax in exp2 domain; per-lane partial row-sum (single final reduce).

typedef __bf16 bf16;
typedef __attribute__((ext_vector_type(4))) __bf16 bf16x4;
typedef __attribute__((ext_vector_type(8))) __bf16 bf16x8;
typedef __attribute__((ext_vector_type(4))) float f32x4;

constexpr int S_ = 2048;
constexpr int D_ = 128;
constexpr int BM = 64;       // Q rows per block
constexpr int BN = 32;       // K rows per tile
constexpr int NIT = S_ / BN; // 64
constexpr int PK = D_ + 8;   // 136 bf16 K pitch (b128-aligned rows, uniform banks)
constexpr int PVT = BN + 8;  // 40 bf16 V^T pitch
constexpr int PP = BN + 8;   // 40 bf16 P pitch

__global__ __launch_bounds__(256, 4) void attn_fwd(
    const float* __restrict__ q, const float* __restrict__ kg,
    const float* __restrict__ vg, const float* __restrict__ sc,
    float* __restrict__ out)
{
    __shared__ __align__(16) bf16 Kh[BN * PK];      // 8704 B
    __shared__ __align__(16) bf16 Kl[BN * PK];      // 8704 B
    __shared__ __align__(16) bf16 Vs[D_ * PVT];     // 10240 B (Vs[d][t] = V[t][d])
    __shared__ __align__(16) bf16 Ps[4 * 16 * PP];  // 5120 B  (wave-private 16x32 P)
    // total 32768 B -> 4 blocks/CU

    const int tid  = threadIdx.x;
    const int wave = tid >> 6;
    const int lane = tid & 63;
    const int l16  = lane & 15;
    const int quad = lane >> 4;

    const int qt = blockIdx.x;   // Q-tile 0..31
    const int bh = blockIdx.y;   // head 0..63

    // scale * log2(e), folded into Q at load: logits come out in exp2 domain.
    const float scale = sc[bh] * 1.44269504088896f;

    const float* qbase = q  + ((size_t)bh * S_ + (size_t)qt * BM) * D_;
    const float* kbase = kg + (size_t)bh * S_ * D_;
    const float* vbase = vg + (size_t)bh * S_ * D_;

    // Q fragments (A-layout: m=l16, k=quad*8+j, +32*ks), scale folded, hi/lo split
    bf16x8 qh[4], ql[4];
    {
        const float* qrow = qbase + (size_t)(wave * 16 + l16) * D_ + quad * 8;
#pragma unroll
        for (int ks = 0; ks < 4; ++ks) {
            float x[8];
            *(float4*)&x[0] = *(const float4*)(qrow + ks * 32);
            *(float4*)&x[4] = *(const float4*)(qrow + ks * 32 + 4);
#pragma unroll
            for (int j = 0; j < 8; ++j) {
                float xs = x[j] * scale;
                bf16 h = (bf16)xs;
                qh[ks][j] = h;
                ql[ks][j] = (bf16)(xs - (float)h);
            }
        }
    }

    f32x4 O[8];                  // O[dblk][r]: row=quad*4+r, col=l16+16*dblk
#pragma unroll
    for (int i = 0; i < 8; ++i) O[i] = (f32x4){0.f, 0.f, 0.f, 0.f};
    float mrow[4] = {-1e30f, -1e30f, -1e30f, -1e30f};
    float Lp[4]   = {0.f, 0.f, 0.f, 0.f};   // per-lane partial row sums

    for (int it = 0; it < NIT; ++it) {
        __syncthreads();  // prev iter's readers done with Kh/Kl/Vs/Ps

        // ---- stage K tile: 32x128 fp32 -> bf16 hi/lo (4 float4/thread) ----
        {
            const float* kt = kbase + (size_t)it * BN * D_;
#pragma unroll
            for (int r = 0; r < 4; ++r) {
                int i = tid + r * 256;          // 1024 float4 chunks
                int row = i >> 5, c = i & 31;
                float4 v = *(const float4*)(kt + row * D_ + c * 4);
                const float* x = (const float*)&v;
                bf16x4 h4, l4;
#pragma unroll
                for (int j = 0; j < 4; ++j) {
                    bf16 h = (bf16)x[j];
                    h4[j] = h;
                    l4[j] = (bf16)(x[j] - (float)h);
                }
                *(bf16x4*)&Kh[row * PK + c * 4] = h4;
                *(bf16x4*)&Kl[row * PK + c * 4] = l4;
            }
            // ---- stage V^T (2 row-pair tasks/thread, conflict-free ushort2) ----
            const float* vt = vbase + (size_t)it * BN * D_;
#pragma unroll
            for (int r = 0; r < 2; ++r) {
                int i = tid + r * 256;          // 512 tasks: 16 t-pairs x 32 c-chunks
                int p = i & 15;                 // rows 2p, 2p+1
                int c = i >> 4;                 // cols 4c..4c+3
                const float* v0 = vt + (2 * p) * D_ + c * 4;
                float4 a0 = *(const float4*)v0;
                float4 a1 = *(const float4*)(v0 + D_);
                const float* x0 = (const float*)&a0;
                const float* x1 = (const float*)&a1;
#pragma unroll
                for (int j = 0; j < 4; ++j) {
                    union { ushort2 u; bf16 b[2]; } pr;
                    pr.b[0] = (bf16)x0[j];
                    pr.b[1] = (bf16)x1[j];
                    *(ushort2*)&Vs[(c * 4 + j) * PVT + 2 * p] = pr.u;
                }
            }
        }
        __syncthreads();

        // ---- QK^T: S[16 x 32] per wave, split-bf16 ----
        f32x4 sacc[2];
        sacc[0] = (f32x4){0.f, 0.f, 0.f, 0.f};
        sacc[1] = (f32x4){0.f, 0.f, 0.f, 0.f};
#pragma unroll
        for (int ks = 0; ks < 4; ++ks) {
#pragma unroll
            for (int nb = 0; nb < 2; ++nb) {
                int off = (nb * 16 + l16) * PK + ks * 32 + quad * 8;
                bf16x8 kh = *(const bf16x8*)&Kh[off];
                bf16x8 kl = *(const bf16x8*)&Kl[off];
                sacc[nb] = __builtin_amdgcn_mfma_f32_16x16x32_bf16(qh[ks], kh, sacc[nb], 0, 0, 0);
                sacc[nb] = __builtin_amdgcn_mfma_f32_16x16x32_bf16(qh[ks], kl, sacc[nb], 0, 0, 0);
                sacc[nb] = __builtin_amdgcn_mfma_f32_16x16x32_bf16(ql[ks], kh, sacc[nb], 0, 0, 0);
            }
        }

        // ---- online softmax (exp2 domain; logits pre-scaled) ----
        float p0[4], p1[4];
#pragma unroll
        for (int r = 0; r < 4; ++r) {
            float m0 = fmaxf(sacc[0][r], sacc[1][r]);
#pragma unroll
            for (int off = 8; off >= 1; off >>= 1)
                m0 = fmaxf(m0, __shfl_xor(m0, off, 64));
            float mnew  = fmaxf(mrow[r], m0);
            float alpha = __builtin_amdgcn_exp2f(mrow[r] - mnew);
            mrow[r] = mnew;
            float e0 = __builtin_amdgcn_exp2f(sacc[0][r] - mnew);
            float e1 = __builtin_amdgcn_exp2f(sacc[1][r] - mnew);
            p0[r] = e0; p1[r] = e1;
            Lp[r] = Lp[r] * alpha + (e0 + e1);   // per-lane partial (2 cols)
#pragma unroll
            for (int d = 0; d < 8; ++d) O[d][r] *= alpha;
        }

        // ---- P: C-layout regs -> wave-private LDS (A-layout read below) ----
        bf16* pw = &Ps[wave * 16 * PP];
#pragma unroll
        for (int r = 0; r < 4; ++r) {
            pw[(quad * 4 + r) * PP + l16]      = (bf16)p0[r];
            pw[(quad * 4 + r) * PP + 16 + l16] = (bf16)p1[r];
        }
        // same-wave DS RAW ordered via lgkmcnt by compiler

        // ---- PV: O[16 x 128] += P[16 x 32] * V[32 x 128] ----
        {
            bf16x8 pa = *(const bf16x8*)&pw[l16 * PP + quad * 8];
#pragma unroll
            for (int d = 0; d < 8; ++d) {
                bf16x8 vb = *(const bf16x8*)&Vs[(d * 16 + l16) * PVT + quad * 8];
                O[d] = __builtin_amdgcn_mfma_f32_16x16x32_bf16(pa, vb, O[d], 0, 0, 0);
            }
        }
    }

    // ---- finalize: reduce per-lane L across the 16 l16-lanes, then store ----
    float rl[4];
#pragma unroll
    for (int r = 0; r < 4; ++r) {
        float L = Lp[r];
#pragma unroll
        for (int off = 8; off >= 1; off >>= 1)
            L += __shfl_xor(L, off, 64);
        rl[r] = 1.0f / L;
    }
    float* og = out + ((size_t)bh * S_ + (size_t)qt * BM + wave * 16) * D_;
#pragma unroll
    for (int d = 0; d < 8; ++d)
#pragma unroll
        for (int r = 0; r < 4; ++r)
            og[(quad * 4 + r) * D_ + d * 16 + l16] = O[d][r] * rl[r];
}

extern "C" void kernel_launch(void* const* d_in, const int* in_sizes, int n_in,
                              void* d_out, int out_size, void* d_ws, size_t ws_size,
                              hipStream_t stream) {
    const float* q  = (const float*)d_in[0];
    const float* k  = (const float*)d_in[1];
    const float* v  = (const float*)d_in[2];
    const float* sc = (const float*)d_in[3];
    float* o = (float*)d_out;
    dim3 grid(S_ / BM, 4 * 16);   // 32 Q-tiles x 64 heads
    attn_fwd<<<grid, 256, 0, stream>>>(q, k, v, sc, o);
}